// Round 1
// 657.824 us; speedup vs baseline: 1.1918x; 1.1918x over previous
//
#include <hip/hip_runtime.h>
#include <stdint.h>

// ---------------------------------------------------------------------------
// SSL_34857954574989: dense SSM with spectral-norm-scaled K.
// w = S x  =>  w_{t+1} = K11n w_t + gamma*K12n u_t ;  y_t = K21n w_t + gamma*K22n u_t
// sigma path: KT(bf16) -> G = K^T K (MFMA GEMM, f32 out) -> 40-step Lanczos on G
// in ONE persistent kernel (32 blocks) with ONE fence-free barrier per
// iteration (per-block generation flags; alpha/beta computed redundantly and
// deterministically in every block) -> Sturm bisection.
// Main path: conv_u -> GEMM1 (Bu bf16, in d_out) -> chunked scan -> GEMM2.
// ---------------------------------------------------------------------------

#define LM 40            // Lanczos steps
#define CHUNK 128        // scan chunk length
#define WARM 12          // scan warm-up steps
#define LBLK 32          // lanczos grid blocks (all co-resident; 32 rows each)

typedef float f32x4 __attribute__((ext_vector_type(4)));
typedef __bf16 bf16x8 __attribute__((ext_vector_type(8)));
typedef unsigned int u32;
typedef unsigned short u16;

static __device__ __forceinline__ u16 f2bf(float f){
  u32 u = __float_as_uint(f);
  u32 r = (u + 0x7fffu + ((u >> 16) & 1u)) >> 16;
  return (u16)r;
}

// K_raw(i,j) evaluated directly (i=row, j=col of the 1024x1024 block matrix)
static __device__ __forceinline__ float kraw_at(int i, int j,
    const float* rho_raw, const float* theta,
    const float* K12, const float* K21, const float* K22){
  if (i < 512){
    if (j < 512){
      if ((i >> 1) != (j >> 1)) return 0.f;
      int p = i >> 1;
      float rho = (1.f / (1.f + expf(-rho_raw[p]))) * 0.999f;
      float c = cosf(theta[p]), s = sinf(theta[p]);
      return ((i & 1) == 0) ? (((j & 1) == 0) ? rho * c : -rho * s)
                            : (((j & 1) == 0) ? rho * s :  rho * c);
    }
    return K12[i * 512 + (j - 512)];
  }
  if (j < 512) return K21[(i - 512) * 512 + j];
  return K22[(i - 512) * 512 + (j - 512)];
}

// KTbf[j][i] = bf16(K_raw(i,j)); thread owns output element (coalesced store)
__global__ __launch_bounds__(256) void build_KT(const float* rho_raw, const float* theta,
    const float* K12, const float* K21, const float* K22, u16* KTbf){
  int idx = blockIdx.x * 256 + threadIdx.x;      // 0 .. 1024*1024-1 (output idx)
  int j = idx >> 10, i = idx & 1023;             // KT row j, col i
  KTbf[idx] = f2bf(kraw_at(i, j, rho_raw, theta, K12, K21, K22));
}

// ------------------------------------------------------------------ init ws
__global__ __launch_bounds__(256) void init_scalars(double* alpha, double* nrm2, u32* flags){
  int t = threadIdx.x;
  if (t < 64) alpha[t] = 0.0;
  if (t < 64) nrm2[t] = 0.0;
  for (int i = t; i < 2048; i += 256) flags[i] = 0u;
}

// ------------------------------------- Lanczos on G = K^T K (single launch)
// Block b owns rows [32b, 32b+32), held entirely in VGPRs (128 f32/thread).
// Per iteration: y(my rows) -> global (double-buffered), ONE barrier, then
// every block redundantly+deterministically computes alpha, w, beta from the
// full y vector (identical FP op order in every block => identical results).
// Barrier: per-block generation flag in its own cacheline (no atomic RMW);
// 32 lanes poll all 32 flags in parallel.
__global__ __launch_bounds__(256, 1) void lanczos_G(const float* __restrict__ G,
    float* W0, float* W1, double* alphaOut, double* nrm2Out, u32* flags){
  __shared__ __align__(16) float vl[1024];  // raw v_{j-1} (full vector)
  __shared__ float red[8];
  int t = threadIdx.x, wave = t >> 6, lane = t & 63;
  int row0 = blockIdx.x * 32;
  float* wbuf[2] = {W0, W1};

  // ---- my 32 G rows -> registers (128 VGPRs/thread). wave w owns rows 8w..8w+7;
  // lane l holds floats [4l+256*i2, +4) of each row.
  f32x4 greg[8][4];
  {
    const float* gbase = G + (size_t)(row0 + wave * 8) * 1024 + lane * 4;
    #pragma unroll
    for (int rr = 0; rr < 8; ++rr)
      #pragma unroll
      for (int i2 = 0; i2 < 4; ++i2)
        greg[rr][i2] = *(const f32x4*)(gbase + (size_t)rr * 1024 + i2 * 256);
  }

  // ---- v0 raw + deterministic redundant norm (identical in every block)
  float vprevreg[4] = {0.f, 0.f, 0.f, 0.f};
  float n2tot;
  {
    float s = 0.f;
    #pragma unroll
    for (int k = 0; k < 4; ++k){
      int i = t + 256 * k;
      float v = sinf(0.613f * (float)i + 0.271f) + 0.3f * sinf(0.0247f * (float)i + 1.3f);
      vl[i] = v;
      s += v * v;
    }
    #pragma unroll
    for (int off = 32; off; off >>= 1) s += __shfl_down(s, off);
    if (lane == 0) red[wave] = s;
    __syncthreads();
    n2tot = (red[0] + red[1]) + (red[2] + red[3]);
  }
  float scal = 1.f / sqrtf(n2tot);     // 1/beta_0
  float betacoef = 0.f;                // no v_prev term at j=1

  for (int j = 1; j <= LM; ++j){
    // ---- y_raw(my rows) = G * v_raw, pure register FMAs; store raw rows
    float* Wt = wbuf[j & 1];
    {
      f32x4 vreg[4];
      #pragma unroll
      for (int i2 = 0; i2 < 4; ++i2)
        vreg[i2] = *((const f32x4*)vl + lane + 64 * i2);
      float yv[8];
      #pragma unroll
      for (int rr = 0; rr < 8; ++rr){
        float s = 0.f;
        #pragma unroll
        for (int i2 = 0; i2 < 4; ++i2){
          f32x4 g = greg[rr][i2], v = vreg[i2];
          s += g[0] * v[0] + g[1] * v[1] + g[2] * v[2] + g[3] * v[3];
        }
        #pragma unroll
        for (int off = 32; off; off >>= 1) s += __shfl_down(s, off);
        yv[rr] = s;
      }
      if (lane == 0){
        #pragma unroll
        for (int rr = 0; rr < 8; ++rr)
          __hip_atomic_store(&Wt[row0 + wave * 8 + rr], yv[rr],
                             __ATOMIC_RELAXED, __HIP_MEMORY_SCOPE_AGENT);
      }
    }

    // ---- ONE barrier: drain my stores, publish generation, poll all blocks
    asm volatile("s_waitcnt vmcnt(0)" ::: "memory");
    __syncthreads();
    if (t == 0)
      __hip_atomic_store(&flags[blockIdx.x * 16], (u32)j,
                         __ATOMIC_RELAXED, __HIP_MEMORY_SCOPE_AGENT);
    if (t < LBLK){
      while (__hip_atomic_load(&flags[t * 16],
                               __ATOMIC_RELAXED, __HIP_MEMORY_SCOPE_AGENT) < (u32)j)
        __builtin_amdgcn_s_sleep(1);
    }
    __syncthreads();

    // ---- redundant deterministic alpha: dot = v_raw^T y_raw
    float yr[4], vr[4];
    float dotp = 0.f;
    #pragma unroll
    for (int k = 0; k < 4; ++k){
      int i = t + 256 * k;
      yr[k] = __hip_atomic_load(&Wt[i], __ATOMIC_RELAXED, __HIP_MEMORY_SCOPE_AGENT);
      vr[k] = vl[i];
      dotp += vr[k] * yr[k];
    }
    #pragma unroll
    for (int off = 32; off; off >>= 1) dotp += __shfl_down(dotp, off);
    if (lane == 0) red[wave] = dotp;
    __syncthreads();
    float dot = (red[0] + red[1]) + (red[2] + red[3]);
    float alpha_f = dot * scal * scal;

    // ---- w = scal*y - alpha*vhat - beta*vprevhat (full vector, redundant)
    float n2 = 0.f;
    #pragma unroll
    for (int k = 0; k < 4; ++k){
      float vh = vr[k] * scal;
      float wv = yr[k] * scal - alpha_f * vh - betacoef * vprevreg[k];
      vprevreg[k] = vh;
      vl[t + 256 * k] = wv;            // raw next v
      n2 += wv * wv;
    }
    #pragma unroll
    for (int off = 32; off; off >>= 1) n2 += __shfl_down(n2, off);
    if (lane == 0) red[4 + wave] = n2;
    __syncthreads();                    // also orders vl[] writes vs next matvec
    n2tot = (red[4] + red[5]) + (red[6] + red[7]);
    if (n2tot < 1e-30f) n2tot = 1e-30f;

    if (blockIdx.x == 0 && t == 0){
      alphaOut[j] = (double)alpha_f;
      nrm2Out[j]  = (double)n2tot;      // beta_j^2
    }
    betacoef = sqrtf(n2tot);
    scal = 1.f / betacoef;
  }
}

// ------------------------------------------------- finalize: sigma + scan coef
// sa[0..LM-1] = alpha_1..alpha_LM ; sb2[i] = beta_i^2 (offdiag between i-1,i)
__global__ __launch_bounds__(256) void finalize_sigma(const double* alpha, const double* beta2,
    const float* rho_raw, const float* theta, const float* log_gamma,
    float* scal, float2* coef){
  __shared__ double sa[LM], sb2[LM + 1];
  __shared__ float sh_inv;
  int t = threadIdx.x;
  if (t < LM) sa[t] = alpha[t];
  if (t < LM + 1) sb2[t] = beta2[t];
  __syncthreads();
  if (t < 64){
    int lane = t;
    double lo = sa[0], hi = sa[0], bmax = 0.0;
    for (int i = 0; i < LM; ++i){
      if (sa[i] > lo) lo = sa[i];
      double bl = (i > 0) ? sqrt(fmax(sb2[i], 0.0)) : 0.0;
      double br = (i < LM - 1) ? sqrt(fmax(sb2[i + 1], 0.0)) : 0.0;
      double g = sa[i] + bl + br;
      if (g > hi) hi = g;
      if (i < LM - 1 && sb2[i + 1] > bmax) bmax = sb2[i + 1];
    }
    hi = hi + 1e-6 * fabs(hi) + 1e-20;
    lo = lo - 1e-6 * fabs(lo) - 1e-20;
    double pivmin = 1e-30 * bmax + 1e-300;
    for (int round = 0; round < 6; ++round){
      double x = lo + (hi - lo) * ((double)(lane + 1) / 65.0);
      double d = sa[0] - x; int cnt = (d < 0.0);
      for (int i = 1; i < LM; ++i){
        if (fabs(d) < pivmin) d = -pivmin;
        d = (sa[i] - x) - sb2[i] / d;
        cnt += (d < 0.0);
      }
      unsigned long long mk = __ballot(cnt >= LM);
      int bpos = (mk == 0ULL) ? 64 : (__ffsll((unsigned long long)mk) - 1);
      double xlo = __shfl(x, (bpos == 0) ? 0 : bpos - 1);
      double xhi = __shfl(x, (bpos == 64) ? 63 : bpos);
      double nlo = (bpos == 0) ? lo : xlo;
      double nhi = (bpos == 64) ? hi : xhi;
      lo = nlo; hi = nhi;
    }
    if (lane == 0){
      double lam = 0.5 * (lo + hi);
      double sig = (lam > 0.0) ? sqrt(lam) : 0.0;
      if (sig < 1e-5) sig = 1e-5;
      double spp = sig + 0.002;
      float inv = (float)(1.0 / spp);
      float g = expf(log_gamma[0]);
      scal[0] = inv; scal[1] = g; scal[2] = g * inv;
      sh_inv = inv;
    }
  }
  __syncthreads();
  float inv = sh_inv;
  float rho = (1.f / (1.f + expf(-rho_raw[t]))) * 0.999f;
  float c = cosf(theta[t]), s = sinf(theta[t]);
  coef[t] = make_float2(rho * c * inv, rho * s * inv);
}

// ------------------------------------------------------------- converts / prep
__global__ __launch_bounds__(256) void conv_u(const float4* u4, u16* X){
  long g = (long)blockIdx.x * 256 + threadIdx.x;     // 8388608 total
  float4 v = u4[g];
  int h4 = (int)(g & 127);
  long row = g >> 7;
  u16* dst = X + row * 1024 + 512 + h4 * 4;
  u32 lo = (u32)f2bf(v.x) | ((u32)f2bf(v.y) << 16);
  u32 hi = (u32)f2bf(v.z) | ((u32)f2bf(v.w) << 16);
  *((uint2*)dst) = make_uint2(lo, hi);
}

__global__ __launch_bounds__(256) void conv_w12(const float4* src, u16* dst){
  long g = (long)blockIdx.x * 256 + threadIdx.x;     // 65536 total
  float4 v = src[g];
  u32 lo = (u32)f2bf(v.x) | ((u32)f2bf(v.y) << 16);
  u32 hi = (u32)f2bf(v.z) | ((u32)f2bf(v.w) << 16);
  ((uint2*)dst)[g] = make_uint2(lo, hi);
}

__global__ __launch_bounds__(256) void build_wcat(const float* K21, const float* K22,
    const float* scal, u16* W){
  int idx = blockIdx.x * 256 + threadIdx.x;          // 524288 total
  int o = idx >> 10, c = idx & 1023;
  float inv = scal[0], gi = scal[2];
  float v = (c < 512) ? K21[o * 512 + c] * inv : K22[o * 512 + (c - 512)] * gi;
  W[idx] = f2bf(v);
}

// w0[b][n] = sum_m S[n][m] * state[b][m]
__global__ __launch_bounds__(256) void w0_matvec(const float* S, const float* state, float* w0){
  int idx = blockIdx.x * 256 + threadIdx.x;          // 8192 total
  int b = idx >> 9, n = idx & 511;
  const float* sr = S + n * 512;
  const float* st = state + b * 512;
  float acc = 0.f;
  for (int m2 = 0; m2 < 512; ++m2) acc += sr[m2] * st[m2];
  w0[idx] = acc;
}

// ------------------------------------------------------------------- the scan
// Bu is bf16 pairs packed in u32: [b][t][256]
__global__ __launch_bounds__(256) void scan_kernel(const u32* Bu, const float2* coef,
    const float* w0, const float* scal, u16* X){
  int b = blockIdx.x >> 5;           // 16 batches
  int c = blockIdx.x & 31;           // 32 chunks of 128
  int p = threadIdx.x;               // 256 pairs
  float2 ab = coef[p];
  float gi = scal[2];
  int t0 = c * CHUNK;
  float wx, wy; int t;
  if (c == 0){ wx = w0[b * 512 + 2 * p]; wy = w0[b * 512 + 2 * p + 1]; t = 0; }
  else { wx = 0.f; wy = 0.f; t = t0 - WARM; }
  const u32* bub = Bu + (size_t)b * 4096 * 256;
  u16* xb = X + (size_t)b * 4096 * 1024;
  for (; t < t0; ++t){
    u32 v = bub[(size_t)t * 256 + p];
    float bx = __uint_as_float(v << 16);
    float by = __uint_as_float(v & 0xffff0000u);
    float nx = ab.x * wx - ab.y * wy + gi * bx;
    float ny = ab.y * wx + ab.x * wy + gi * by;
    wx = nx; wy = ny;
  }
  for (; t < t0 + CHUNK; ++t){
    u32 pk = (u32)f2bf(wx) | ((u32)f2bf(wy) << 16);
    *(u32*)(xb + (size_t)t * 1024 + 2 * p) = pk;
    u32 v = bub[(size_t)t * 256 + p];
    float bx = __uint_as_float(v << 16);
    float by = __uint_as_float(v & 0xffff0000u);
    float nx = ab.x * wx - ab.y * wy + gi * bx;
    float ny = ab.y * wx + ab.x * wy + gi * by;
    wx = nx; wy = ny;
  }
}

// ------------------------------------------------------------------ bf16 GEMM
// C[M x N] = A[M x K] bf16 * B[N x K]^T bf16. 128x128 tile, BK=64.
// XCD-partitioned block swizzle; XOR-swizzled LDS layout.
static __device__ __forceinline__ void gload16(const u16* g, u16* l){
  __builtin_amdgcn_global_load_lds((const __attribute__((address_space(1))) u32*)g,
                                   (__attribute__((address_space(3))) u32*)l, 16, 0, 0);
}

template <typename OT>
__global__ __launch_bounds__(256) void gemm_nt(const u16* __restrict__ A, int lda,
    const u16* __restrict__ B, int ldb, OT* __restrict__ C, int ldc, int K, int ntn){
  __shared__ u16 As[128 * 64];
  __shared__ u16 Bs[128 * 64];
  int g = blockIdx.x;
  int xcd = g & 7, local = g >> 3;
  int mper = gridDim.x >> 3; mper /= ntn;     // m-tiles per xcd
  int bn = local % ntn;
  int bm = xcd * mper + local / ntn;
  int t = threadIdx.x, lane = t & 63, wave = t >> 6;
  int lrow = t >> 3;                          // 0..31
  int swz = (((t & 7) ^ (lrow & 7)) << 3);    // XOR-swizzled col offset (elems)
  const u16* Ag = A + (size_t)(bm * 128 + lrow) * lda + swz;
  const u16* Bg = B + (size_t)(bn * 128 + lrow) * ldb + swz;
  u16* Asd = As + t * 8;
  u16* Bsd = Bs + t * 8;
  f32x4 acc[4][4];
  #pragma unroll
  for (int mi = 0; mi < 4; ++mi)
    #pragma unroll
    for (int ni = 0; ni < 4; ++ni) acc[mi][ni] = (f32x4){0.f, 0.f, 0.f, 0.f};
  int wm = (wave & 1) << 6, wn = (wave >> 1) << 6;
  int fr = lane & 15, cbb = lane >> 4;
  for (int kt = 0; kt < K; kt += 64){
    __syncthreads();
    #pragma unroll
    for (int r = 0; r < 4; ++r){
      gload16(Ag + (size_t)(r * 32) * lda + kt, Asd + r * 2048);
      gload16(Bg + (size_t)(r * 32) * ldb + kt, Bsd + r * 2048);
    }
    __syncthreads();
    #pragma unroll
    for (int kk = 0; kk < 2; ++kk){
      bf16x8 af[4], bfr[4];
      #pragma unroll
      for (int mi = 0; mi < 4; ++mi){
        int row = wm + mi * 16 + fr;
        int pcb = ((kk << 2) + cbb) ^ (fr & 7);
        af[mi] = *(const bf16x8*)(As + row * 64 + pcb * 8);
      }
      #pragma unroll
      for (int ni = 0; ni < 4; ++ni){
        int row = wn + ni * 16 + fr;
        int pcb = ((kk << 2) + cbb) ^ (fr & 7);
        bfr[ni] = *(const bf16x8*)(Bs + row * 64 + pcb * 8);
      }
      #pragma unroll
      for (int mi = 0; mi < 4; ++mi)
        #pragma unroll
        for (int ni = 0; ni < 4; ++ni)
          acc[mi][ni] = __builtin_amdgcn_mfma_f32_16x16x32_bf16(af[mi], bfr[ni], acc[mi][ni], 0, 0, 0);
    }
  }
  int rq = lane >> 4;
  #pragma unroll
  for (int mi = 0; mi < 4; ++mi)
    #pragma unroll
    for (int ni = 0; ni < 4; ++ni){
      size_t base = (size_t)(bm * 128 + wm + mi * 16 + rq * 4) * ldc
                  + (size_t)(bn * 128 + wn + ni * 16 + fr);
      #pragma unroll
      for (int r = 0; r < 4; ++r){
        if constexpr (sizeof(OT) == 4) C[base + (size_t)r * ldc] = acc[mi][ni][r];
        else                           C[base + (size_t)r * ldc] = (OT)f2bf(acc[mi][ni][r]);
      }
    }
}

// ------------------------------------------------------------------- launcher
extern "C" void kernel_launch(void* const* d_in, const int* in_sizes, int n_in,
                              void* d_out, int out_size, void* d_ws, size_t ws_size,
                              hipStream_t stream){
  const float* u        = (const float*)d_in[0];
  const float* state    = (const float*)d_in[1];
  const float* S        = (const float*)d_in[2];
  const float* rho_raw  = (const float*)d_in[3];
  const float* theta    = (const float*)d_in[4];
  const float* K12      = (const float*)d_in[5];
  const float* K21      = (const float*)d_in[6];
  const float* K22      = (const float*)d_in[7];
  const float* log_gamma= (const float*)d_in[8];

  char* w = (char*)d_ws;
  size_t off = 0;
  auto alloc = [&](size_t bytes)->void*{
    void* p = w + off;
    off = (off + bytes + 255) & ~(size_t)255;
    return p;
  };
  double* alpha = (double*)alloc(64 * 8);
  double* nrm2  = (double*)alloc(64 * 8);
  u32*    flags = (u32*)alloc(2048 * 4);
  float*  scal  = (float*)alloc(64);
  float2* coef  = (float2*)alloc(256 * 8);
  float*  W0    = (float*)alloc(1024 * 4);
  float*  W1    = (float*)alloc(1024 * 4);
  float*  w0    = (float*)alloc(16 * 512 * 4);
  u16*    KTbf  = (u16*)alloc((size_t)1024 * 1024 * 2);
  float*  G     = (float*)alloc((size_t)1024 * 1024 * 4);
  u16*    W12   = (u16*)alloc((size_t)512 * 512 * 2);
  u16*    Wcat  = (u16*)alloc((size_t)512 * 1024 * 2);
  u16*    Xb    = (u16*)alloc((size_t)65536 * 1024 * 2);
  // Bu (bf16, 67 MB) aliases d_out; consumed by scan before GEMM2 overwrites.
  u16*    Bu    = (u16*)d_out;

  init_scalars<<<1, 256, 0, stream>>>(alpha, nrm2, flags);
  build_KT<<<4096, 256, 0, stream>>>(rho_raw, theta, K12, K21, K22, KTbf);
  // G = K^T K = KT @ KT^T  (M=N=K=1024, f32 out)
  gemm_nt<float><<<64, 256, 0, stream>>>(KTbf, 1024, KTbf, 1024, G, 1024, 1024, 8);
  lanczos_G<<<LBLK, 256, 0, stream>>>(G, W0, W1, alpha, nrm2, flags);
  finalize_sigma<<<1, 256, 0, stream>>>(alpha + 1, nrm2, rho_raw, theta, log_gamma, scal, coef);

  conv_u<<<32768, 256, 0, stream>>>((const float4*)u, Xb);
  conv_w12<<<256, 256, 0, stream>>>((const float4*)K12, W12);
  build_wcat<<<2048, 256, 0, stream>>>(K21, K22, scal, Wcat);
  w0_matvec<<<32, 256, 0, stream>>>(S, state, w0);

  // GEMM1: Bu(bf16) = u_bf16 @ K12^T   (M=65536, N=512, K=512)
  gemm_nt<u16><<<2048, 256, 0, stream>>>(Xb + 512, 1024, W12, 512, Bu, 512, 512, 4);
  // scan: pre (bf16) into X[:, 0:512]
  scan_kernel<<<512, 256, 0, stream>>>((const u32*)Bu, coef, w0, scal, Xb);
  // GEMM2: y = [pre|u] @ [K21n | gamma*K22n]^T  (M=65536, N=512, K=1024)
  gemm_nt<float><<<2048, 256, 0, stream>>>(Xb, 1024, Wcat, 1024, (float*)d_out, 512, 1024, 4);
}

// Round 2
// 618.168 us; speedup vs baseline: 1.2682x; 1.0641x over previous
//
#include <hip/hip_runtime.h>
#include <stdint.h>

// ---------------------------------------------------------------------------
// SSL_34857954574989: dense SSM with spectral-norm-scaled K.
// w = S x  =>  w_{t+1} = K11n w_t + gamma*K12n u_t ;  y_t = K21n w_t + gamma*K22n u_t
// sigma path: KT(bf16) -> G = K^T K (MFMA GEMM, f32 out) -> 40-step Lanczos on G
// in ONE persistent kernel (32 blocks). Cross-block exchange is ONE leg per
// iteration: each y element is published as a self-tagged 8-byte record
// {f32 y, u32 iter}; readers poll the records directly (tag==j => payload
// valid). Double-buffered by iteration parity. alpha/beta computed
// redundantly+deterministically in every block. -> Sturm bisection.
// Main path: prep (conv_u/conv_w12/w0) -> GEMM1 (Bu bf16, in d_out) -> scan
// -> GEMM2.
// ---------------------------------------------------------------------------

#define LM 40            // Lanczos steps
#define CHUNK 128        // scan chunk length
#define WARM 12          // scan warm-up steps
#define LBLK 32          // lanczos grid blocks (all co-resident; 32 rows each)

typedef float f32x4 __attribute__((ext_vector_type(4)));
typedef __bf16 bf16x8 __attribute__((ext_vector_type(8)));
typedef unsigned int u32;
typedef unsigned long long u64;
typedef unsigned short u16;

static __device__ __forceinline__ u16 f2bf(float f){
  u32 u = __float_as_uint(f);
  u32 r = (u + 0x7fffu + ((u >> 16) & 1u)) >> 16;
  return (u16)r;
}

// K_raw(i,j) evaluated directly (i=row, j=col of the 1024x1024 block matrix)
static __device__ __forceinline__ float kraw_at(int i, int j,
    const float* rho_raw, const float* theta,
    const float* K12, const float* K21, const float* K22){
  if (i < 512){
    if (j < 512){
      if ((i >> 1) != (j >> 1)) return 0.f;
      int p = i >> 1;
      float rho = (1.f / (1.f + expf(-rho_raw[p]))) * 0.999f;
      float c = cosf(theta[p]), s = sinf(theta[p]);
      return ((i & 1) == 0) ? (((j & 1) == 0) ? rho * c : -rho * s)
                            : (((j & 1) == 0) ? rho * s :  rho * c);
    }
    return K12[i * 512 + (j - 512)];
  }
  if (j < 512) return K21[(i - 512) * 512 + j];
  return K22[(i - 512) * 512 + (j - 512)];
}

// KTbf[j][i] = bf16(K_raw(i,j)); thread owns output element (coalesced store).
// Extra block (blockIdx == 4096) zeroes the lanczos scalars + record buffers.
__global__ __launch_bounds__(256) void build_KT(const float* rho_raw, const float* theta,
    const float* K12, const float* K21, const float* K22, u16* KTbf,
    double* alpha, double* nrm2, u64* rec){
  if (blockIdx.x == 4096){
    int t = threadIdx.x;
    if (t < 64){ alpha[t] = 0.0; nrm2[t] = 0.0; }
    for (int i = t; i < 2048; i += 256) rec[i] = 0ull;
    return;
  }
  int idx = blockIdx.x * 256 + threadIdx.x;      // 0 .. 1024*1024-1 (output idx)
  int j = idx >> 10, i = idx & 1023;             // KT row j, col i
  KTbf[idx] = f2bf(kraw_at(i, j, rho_raw, theta, K12, K21, K22));
}

// ------------------------------------- Lanczos on G = K^T K (single launch)
// Block b owns rows [32b, 32b+32), held entirely in VGPRs (128 f32/thread).
// Per iteration: publish my 32 y-values as self-tagged 8B records (ONE
// agent-scope leg), poll all 1024 records, then redundantly+deterministically
// compute alpha, w, beta (identical FP op order in every block => identical
// results). rec double-buffered by iteration parity (tag exact-match; a
// writer cannot get 2 rounds ahead of any reader by transitive dependency).
__global__ __launch_bounds__(256, 1) void lanczos_G(const float* __restrict__ G,
    u64* rec, double* alphaOut, double* nrm2Out){
  __shared__ __align__(16) float vl[1024];  // raw v_{j-1} (full vector)
  __shared__ float red[8];
  int t = threadIdx.x, wave = t >> 6, lane = t & 63;
  int row0 = blockIdx.x * 32;

  // ---- my 32 G rows -> registers (128 f32/thread). wave w owns rows 8w..8w+7;
  // lane l holds floats [4l+256*i2, +4) of each row.
  f32x4 greg[8][4];
  {
    const float* gbase = G + (size_t)(row0 + wave * 8) * 1024 + lane * 4;
    #pragma unroll
    for (int rr = 0; rr < 8; ++rr)
      #pragma unroll
      for (int i2 = 0; i2 < 4; ++i2)
        greg[rr][i2] = *(const f32x4*)(gbase + (size_t)rr * 1024 + i2 * 256);
  }

  // ---- v0 raw + deterministic redundant norm (identical in every block)
  float vprevreg[4] = {0.f, 0.f, 0.f, 0.f};
  float n2tot;
  {
    float s = 0.f;
    #pragma unroll
    for (int k = 0; k < 4; ++k){
      int i = t + 256 * k;
      float v = sinf(0.613f * (float)i + 0.271f) + 0.3f * sinf(0.0247f * (float)i + 1.3f);
      vl[i] = v;
      s += v * v;
    }
    #pragma unroll
    for (int off = 32; off; off >>= 1) s += __shfl_down(s, off);
    if (lane == 0) red[wave] = s;
    __syncthreads();
    n2tot = (red[0] + red[1]) + (red[2] + red[3]);
  }
  float scal = 1.f / sqrtf(n2tot);     // 1/beta_0
  float betacoef = 0.f;                // no v_prev term at j=1

  for (int j = 1; j <= LM; ++j){
    u64* rb = rec + ((j & 1) ? 0 : 1024);   // double buffer by parity
    // ---- y_raw(my rows) = G * v_raw, register FMAs; butterfly reduce so
    // lanes 0..7 publish their row's self-tagged record immediately.
    {
      f32x4 vreg[4];
      #pragma unroll
      for (int i2 = 0; i2 < 4; ++i2)
        vreg[i2] = *((const f32x4*)vl + lane + 64 * i2);
      u64 myrec = 0ull;
      #pragma unroll
      for (int rr = 0; rr < 8; ++rr){
        float s = 0.f;
        #pragma unroll
        for (int i2 = 0; i2 < 4; ++i2){
          f32x4 g = greg[rr][i2], v = vreg[i2];
          s += g[0] * v[0] + g[1] * v[1] + g[2] * v[2] + g[3] * v[3];
        }
        #pragma unroll
        for (int off = 32; off; off >>= 1) s += __shfl_xor(s, off);
        if (lane == rr)
          myrec = ((u64)(u32)j << 32) | (u64)__float_as_uint(s);
      }
      if (lane < 8)
        __hip_atomic_store(&rb[row0 + wave * 8 + lane], myrec,
                           __ATOMIC_RELAXED, __HIP_MEMORY_SCOPE_AGENT);
    }

    // ---- poll the full y vector: tag==j means payload valid (same 8 bytes)
    float yr[4], vr[4];
    {
      u32 need = 0xFu;
      u64 rv[4];
      while (need){
        #pragma unroll
        for (int k = 0; k < 4; ++k){
          if (need & (1u << k)){
            u64 r = __hip_atomic_load(&rb[t + 256 * k],
                                      __ATOMIC_RELAXED, __HIP_MEMORY_SCOPE_AGENT);
            if ((u32)(r >> 32) == (u32)j){ rv[k] = r; need &= ~(1u << k); }
          }
        }
        if (need) __builtin_amdgcn_s_sleep(1);
      }
      #pragma unroll
      for (int k = 0; k < 4; ++k){
        yr[k] = __uint_as_float((u32)rv[k]);
        vr[k] = vl[t + 256 * k];
      }
    }

    // ---- redundant deterministic alpha: dot = v_raw^T y_raw
    float dotp = 0.f;
    #pragma unroll
    for (int k = 0; k < 4; ++k) dotp += vr[k] * yr[k];
    #pragma unroll
    for (int off = 32; off; off >>= 1) dotp += __shfl_down(dotp, off);
    if (lane == 0) red[wave] = dotp;
    __syncthreads();
    float dot = (red[0] + red[1]) + (red[2] + red[3]);
    float alpha_f = dot * scal * scal;

    // ---- w = scal*y - alpha*vhat - beta*vprevhat (full vector, redundant)
    float n2 = 0.f;
    #pragma unroll
    for (int k = 0; k < 4; ++k){
      float vh = vr[k] * scal;
      float wv = yr[k] * scal - alpha_f * vh - betacoef * vprevreg[k];
      vprevreg[k] = vh;
      vl[t + 256 * k] = wv;            // raw next v
      n2 += wv * wv;
    }
    #pragma unroll
    for (int off = 32; off; off >>= 1) n2 += __shfl_down(n2, off);
    if (lane == 0) red[4 + wave] = n2;
    __syncthreads();                    // also orders vl[] writes vs next matvec
    n2tot = (red[4] + red[5]) + (red[6] + red[7]);
    if (n2tot < 1e-30f) n2tot = 1e-30f;

    if (blockIdx.x == 0 && t == 0){
      alphaOut[j] = (double)alpha_f;
      nrm2Out[j]  = (double)n2tot;      // beta_j^2
    }
    betacoef = sqrtf(n2tot);
    scal = 1.f / betacoef;
  }
}

// ------------------------------------------------- finalize: sigma + scan coef
// sa[0..LM-1] = alpha_1..alpha_LM ; sb2[i] = beta_i^2 (offdiag between i-1,i)
__global__ __launch_bounds__(256) void finalize_sigma(const double* alpha, const double* beta2,
    const float* rho_raw, const float* theta, const float* log_gamma,
    float* scal, float2* coef){
  __shared__ double sa[LM], sb2[LM + 1];
  __shared__ float sh_inv;
  int t = threadIdx.x;
  if (t < LM) sa[t] = alpha[t];
  if (t < LM + 1) sb2[t] = beta2[t];
  __syncthreads();
  if (t < 64){
    int lane = t;
    double lo = sa[0], hi = sa[0], bmax = 0.0;
    for (int i = 0; i < LM; ++i){
      if (sa[i] > lo) lo = sa[i];
      double bl = (i > 0) ? sqrt(fmax(sb2[i], 0.0)) : 0.0;
      double br = (i < LM - 1) ? sqrt(fmax(sb2[i + 1], 0.0)) : 0.0;
      double g = sa[i] + bl + br;
      if (g > hi) hi = g;
      if (i < LM - 1 && sb2[i + 1] > bmax) bmax = sb2[i + 1];
    }
    hi = hi + 1e-6 * fabs(hi) + 1e-20;
    lo = lo - 1e-6 * fabs(lo) - 1e-20;
    double pivmin = 1e-30 * bmax + 1e-300;
    for (int round = 0; round < 6; ++round){
      double x = lo + (hi - lo) * ((double)(lane + 1) / 65.0);
      double d = sa[0] - x; int cnt = (d < 0.0);
      for (int i = 1; i < LM; ++i){
        if (fabs(d) < pivmin) d = -pivmin;
        d = (sa[i] - x) - sb2[i] / d;
        cnt += (d < 0.0);
      }
      unsigned long long mk = __ballot(cnt >= LM);
      int bpos = (mk == 0ULL) ? 64 : (__ffsll((unsigned long long)mk) - 1);
      double xlo = __shfl(x, (bpos == 0) ? 0 : bpos - 1);
      double xhi = __shfl(x, (bpos == 64) ? 63 : bpos);
      double nlo = (bpos == 0) ? lo : xlo;
      double nhi = (bpos == 64) ? hi : xhi;
      lo = nlo; hi = nhi;
    }
    if (lane == 0){
      double lam = 0.5 * (lo + hi);
      double sig = (lam > 0.0) ? sqrt(lam) : 0.0;
      if (sig < 1e-5) sig = 1e-5;
      double spp = sig + 0.002;
      float inv = (float)(1.0 / spp);
      float g = expf(log_gamma[0]);
      scal[0] = inv; scal[1] = g; scal[2] = g * inv;
      sh_inv = inv;
    }
  }
  __syncthreads();
  float inv = sh_inv;
  float rho = (1.f / (1.f + expf(-rho_raw[t]))) * 0.999f;
  float c = cosf(theta[t]), s = sinf(theta[t]);
  coef[t] = make_float2(rho * c * inv, rho * s * inv);
}

// --------------------------------------- merged prep: conv_u / conv_w12 / w0
__global__ __launch_bounds__(256) void prep_main(const float4* u4, u16* X,
    const float4* k12_4, u16* W12, const float* S, const float* state, float* w0){
  int blk = blockIdx.x;
  if (blk < 32768){
    long g = (long)blk * 256 + threadIdx.x;          // 8388608 total
    float4 v = u4[g];
    int h4 = (int)(g & 127);
    long row = g >> 7;
    u16* dst = X + row * 1024 + 512 + h4 * 4;
    u32 lo = (u32)f2bf(v.x) | ((u32)f2bf(v.y) << 16);
    u32 hi = (u32)f2bf(v.z) | ((u32)f2bf(v.w) << 16);
    *((uint2*)dst) = make_uint2(lo, hi);
  } else if (blk < 32768 + 256){
    long g = (long)(blk - 32768) * 256 + threadIdx.x; // 65536 total
    float4 v = k12_4[g];
    u32 lo = (u32)f2bf(v.x) | ((u32)f2bf(v.y) << 16);
    u32 hi = (u32)f2bf(v.z) | ((u32)f2bf(v.w) << 16);
    ((uint2*)W12)[g] = make_uint2(lo, hi);
  } else {
    int idx = (blk - 33024) * 256 + threadIdx.x;      // 8192 total
    int b = idx >> 9, n = idx & 511;
    const float* sr = S + n * 512;
    const float* st = state + b * 512;
    float acc = 0.f;
    for (int m2 = 0; m2 < 512; ++m2) acc += sr[m2] * st[m2];
    w0[idx] = acc;
  }
}

__global__ __launch_bounds__(256) void build_wcat(const float* K21, const float* K22,
    const float* scal, u16* W){
  int idx = blockIdx.x * 256 + threadIdx.x;          // 524288 total
  int o = idx >> 10, c = idx & 1023;
  float inv = scal[0], gi = scal[2];
  float v = (c < 512) ? K21[o * 512 + c] * inv : K22[o * 512 + (c - 512)] * gi;
  W[idx] = f2bf(v);
}

// ------------------------------------------------------------------- the scan
// Bu is bf16 pairs packed in u32: [b][t][256]
__global__ __launch_bounds__(256) void scan_kernel(const u32* Bu, const float2* coef,
    const float* w0, const float* scal, u16* X){
  int b = blockIdx.x >> 5;           // 16 batches
  int c = blockIdx.x & 31;           // 32 chunks of 128
  int p = threadIdx.x;               // 256 pairs
  float2 ab = coef[p];
  float gi = scal[2];
  int t0 = c * CHUNK;
  float wx, wy; int t;
  if (c == 0){ wx = w0[b * 512 + 2 * p]; wy = w0[b * 512 + 2 * p + 1]; t = 0; }
  else { wx = 0.f; wy = 0.f; t = t0 - WARM; }
  const u32* bub = Bu + (size_t)b * 4096 * 256;
  u16* xb = X + (size_t)b * 4096 * 1024;
  for (; t < t0; ++t){
    u32 v = bub[(size_t)t * 256 + p];
    float bx = __uint_as_float(v << 16);
    float by = __uint_as_float(v & 0xffff0000u);
    float nx = ab.x * wx - ab.y * wy + gi * bx;
    float ny = ab.y * wx + ab.x * wy + gi * by;
    wx = nx; wy = ny;
  }
  for (; t < t0 + CHUNK; ++t){
    u32 pk = (u32)f2bf(wx) | ((u32)f2bf(wy) << 16);
    *(u32*)(xb + (size_t)t * 1024 + 2 * p) = pk;
    u32 v = bub[(size_t)t * 256 + p];
    float bx = __uint_as_float(v << 16);
    float by = __uint_as_float(v & 0xffff0000u);
    float nx = ab.x * wx - ab.y * wy + gi * bx;
    float ny = ab.y * wx + ab.x * wy + gi * by;
    wx = nx; wy = ny;
  }
}

// ------------------------------------------------------------------ bf16 GEMM
// C[M x N] = A[M x K] bf16 * B[N x K]^T bf16. 128x128 tile, BK=64.
// XCD-partitioned block swizzle; XOR-swizzled LDS layout.
static __device__ __forceinline__ void gload16(const u16* g, u16* l){
  __builtin_amdgcn_global_load_lds((const __attribute__((address_space(1))) u32*)g,
                                   (__attribute__((address_space(3))) u32*)l, 16, 0, 0);
}

template <typename OT>
__global__ __launch_bounds__(256) void gemm_nt(const u16* __restrict__ A, int lda,
    const u16* __restrict__ B, int ldb, OT* __restrict__ C, int ldc, int K, int ntn){
  __shared__ u16 As[128 * 64];
  __shared__ u16 Bs[128 * 64];
  int g = blockIdx.x;
  int xcd = g & 7, local = g >> 3;
  int mper = gridDim.x >> 3; mper /= ntn;     // m-tiles per xcd
  int bn = local % ntn;
  int bm = xcd * mper + local / ntn;
  int t = threadIdx.x, lane = t & 63, wave = t >> 6;
  int lrow = t >> 3;                          // 0..31
  int swz = (((t & 7) ^ (lrow & 7)) << 3);    // XOR-swizzled col offset (elems)
  const u16* Ag = A + (size_t)(bm * 128 + lrow) * lda + swz;
  const u16* Bg = B + (size_t)(bn * 128 + lrow) * ldb + swz;
  u16* Asd = As + t * 8;
  u16* Bsd = Bs + t * 8;
  f32x4 acc[4][4];
  #pragma unroll
  for (int mi = 0; mi < 4; ++mi)
    #pragma unroll
    for (int ni = 0; ni < 4; ++ni) acc[mi][ni] = (f32x4){0.f, 0.f, 0.f, 0.f};
  int wm = (wave & 1) << 6, wn = (wave >> 1) << 6;
  int fr = lane & 15, cbb = lane >> 4;
  for (int kt = 0; kt < K; kt += 64){
    __syncthreads();
    #pragma unroll
    for (int r = 0; r < 4; ++r){
      gload16(Ag + (size_t)(r * 32) * lda + kt, Asd + r * 2048);
      gload16(Bg + (size_t)(r * 32) * ldb + kt, Bsd + r * 2048);
    }
    __syncthreads();
    #pragma unroll
    for (int kk = 0; kk < 2; ++kk){
      bf16x8 af[4], bfr[4];
      #pragma unroll
      for (int mi = 0; mi < 4; ++mi){
        int row = wm + mi * 16 + fr;
        int pcb = ((kk << 2) + cbb) ^ (fr & 7);
        af[mi] = *(const bf16x8*)(As + row * 64 + pcb * 8);
      }
      #pragma unroll
      for (int ni = 0; ni < 4; ++ni){
        int row = wn + ni * 16 + fr;
        int pcb = ((kk << 2) + cbb) ^ (fr & 7);
        bfr[ni] = *(const bf16x8*)(Bs + row * 64 + pcb * 8);
      }
      #pragma unroll
      for (int mi = 0; mi < 4; ++mi)
        #pragma unroll
        for (int ni = 0; ni < 4; ++ni)
          acc[mi][ni] = __builtin_amdgcn_mfma_f32_16x16x32_bf16(af[mi], bfr[ni], acc[mi][ni], 0, 0, 0);
    }
  }
  int rq = lane >> 4;
  #pragma unroll
  for (int mi = 0; mi < 4; ++mi)
    #pragma unroll
    for (int ni = 0; ni < 4; ++ni){
      size_t base = (size_t)(bm * 128 + wm + mi * 16 + rq * 4) * ldc
                  + (size_t)(bn * 128 + wn + ni * 16 + fr);
      #pragma unroll
      for (int r = 0; r < 4; ++r){
        if constexpr (sizeof(OT) == 4) C[base + (size_t)r * ldc] = acc[mi][ni][r];
        else                           C[base + (size_t)r * ldc] = (OT)f2bf(acc[mi][ni][r]);
      }
    }
}

// ------------------------------------------------------------------- launcher
extern "C" void kernel_launch(void* const* d_in, const int* in_sizes, int n_in,
                              void* d_out, int out_size, void* d_ws, size_t ws_size,
                              hipStream_t stream){
  const float* u        = (const float*)d_in[0];
  const float* state    = (const float*)d_in[1];
  const float* S        = (const float*)d_in[2];
  const float* rho_raw  = (const float*)d_in[3];
  const float* theta    = (const float*)d_in[4];
  const float* K12      = (const float*)d_in[5];
  const float* K21      = (const float*)d_in[6];
  const float* K22      = (const float*)d_in[7];
  const float* log_gamma= (const float*)d_in[8];

  char* w = (char*)d_ws;
  size_t off = 0;
  auto alloc = [&](size_t bytes)->void*{
    void* p = w + off;
    off = (off + bytes + 255) & ~(size_t)255;
    return p;
  };
  double* alpha = (double*)alloc(64 * 8);
  double* nrm2  = (double*)alloc(64 * 8);
  u64*    rec   = (u64*)alloc(2048 * 8);       // 2 x 1024 self-tagged records
  float*  scal  = (float*)alloc(64);
  float2* coef  = (float2*)alloc(256 * 8);
  float*  w0    = (float*)alloc(16 * 512 * 4);
  u16*    KTbf  = (u16*)alloc((size_t)1024 * 1024 * 2);
  float*  G     = (float*)alloc((size_t)1024 * 1024 * 4);
  u16*    W12   = (u16*)alloc((size_t)512 * 512 * 2);
  u16*    Wcat  = (u16*)alloc((size_t)512 * 1024 * 2);
  u16*    Xb    = (u16*)alloc((size_t)65536 * 1024 * 2);
  // Bu (bf16, 67 MB) aliases d_out; consumed by scan before GEMM2 overwrites.
  u16*    Bu    = (u16*)d_out;

  build_KT<<<4097, 256, 0, stream>>>(rho_raw, theta, K12, K21, K22, KTbf, alpha, nrm2, rec);
  // G = K^T K = KT @ KT^T  (M=N=K=1024, f32 out)
  gemm_nt<float><<<64, 256, 0, stream>>>(KTbf, 1024, KTbf, 1024, G, 1024, 1024, 8);
  lanczos_G<<<LBLK, 256, 0, stream>>>(G, rec, alpha, nrm2);
  finalize_sigma<<<1, 256, 0, stream>>>(alpha + 1, nrm2, rho_raw, theta, log_gamma, scal, coef);

  prep_main<<<33056, 256, 0, stream>>>((const float4*)u, Xb, (const float4*)K12, W12, S, state, w0);
  build_wcat<<<2048, 256, 0, stream>>>(K21, K22, scal, Wcat);

  // GEMM1: Bu(bf16) = u_bf16 @ K12^T   (M=65536, N=512, K=512)
  gemm_nt<u16><<<2048, 256, 0, stream>>>(Xb + 512, 1024, W12, 512, Bu, 512, 512, 4);
  // scan: pre (bf16) into X[:, 0:512]
  scan_kernel<<<512, 256, 0, stream>>>((const u32*)Bu, coef, w0, scal, Xb);
  // GEMM2: y = [pre|u] @ [K21n | gamma*K22n]^T  (M=65536, N=512, K=1024)
  gemm_nt<float><<<2048, 256, 0, stream>>>(Xb, 1024, Wcat, 1024, (float*)d_out, 512, 1024, 4);
}

// Round 4
// 552.071 us; speedup vs baseline: 1.4201x; 1.1197x over previous
//
#include <hip/hip_runtime.h>
#include <stdint.h>

// ---------------------------------------------------------------------------
// SSL_34857954574989: dense SSM with spectral-norm-scaled K.
// w = S x  =>  w_{t+1} = K11n w_t + gamma*K12n u_t ;  y_t = K21n w_t + gamma*K22n u_t
//
// 5 fused launches (role-split by blockIdx; all roles independent inside a
// launch -> deadlock-free regardless of dispatch order):
//  kA: build_KT(bf16) + conv_w12 + rec init
//  kB: G = K^T K (MFMA GEMM, 64 blocks, first) || conv_u || w0_matvec
//  kC: 40-step Lanczos on G (32 blocks, first; self-tagged 8B record exchange,
//      one leg/iter; alpha/beta redundant+deterministic; Sturm bisection +
//      scan-coef folded into block 0 tail)  ||  GEMM1 (Bu = u @ K12^T, 2048
//      blocks, sigma-independent -> hidden under lanczos latency)
//  kD: scan (512 blocks, first) || build_wcat
//  GEMM2: y = [pre|u] @ [K21n | gamma*K22n]^T
// ---------------------------------------------------------------------------

#define LM 40            // Lanczos steps
#define CHUNK 128        // scan chunk length
#define WARM 12          // scan warm-up steps
#define LBLK 32          // lanczos blocks (32 rows each)

typedef float f32x4 __attribute__((ext_vector_type(4)));
typedef __bf16 bf16x8 __attribute__((ext_vector_type(8)));
typedef unsigned int u32;
typedef unsigned long long u64;
typedef unsigned short u16;

static __device__ __forceinline__ u16 f2bf(float f){
  u32 u = __float_as_uint(f);
  u32 r = (u + 0x7fffu + ((u >> 16) & 1u)) >> 16;
  return (u16)r;
}

// K_raw(i,j) evaluated directly (i=row, j=col of the 1024x1024 block matrix)
static __device__ __forceinline__ float kraw_at(int i, int j,
    const float* rho_raw, const float* theta,
    const float* K12, const float* K21, const float* K22){
  if (i < 512){
    if (j < 512){
      if ((i >> 1) != (j >> 1)) return 0.f;
      int p = i >> 1;
      float rho = (1.f / (1.f + expf(-rho_raw[p]))) * 0.999f;
      float c = cosf(theta[p]), s = sinf(theta[p]);
      return ((i & 1) == 0) ? (((j & 1) == 0) ? rho * c : -rho * s)
                            : (((j & 1) == 0) ? rho * s :  rho * c);
    }
    return K12[i * 512 + (j - 512)];
  }
  if (j < 512) return K21[(i - 512) * 512 + j];
  return K22[(i - 512) * 512 + (j - 512)];
}

// ------------------------------------------------------------------ bf16 GEMM
// C[M x N] = A[M x K] bf16 * B[N x K]^T bf16. 128x128 tile, BK=64.
// XCD-partitioned block swizzle; XOR-swizzled LDS layout. Callable from fused
// kernels: g = local block id, ngrid = local grid size.
static __device__ __forceinline__ void gload16(const u16* g, u16* l){
  __builtin_amdgcn_global_load_lds((const __attribute__((address_space(1))) u32*)g,
                                   (__attribute__((address_space(3))) u32*)l, 16, 0, 0);
}

template <typename OT>
static __device__ __forceinline__ void gemm_body(int g, int ngrid,
    const u16* __restrict__ A, int lda, const u16* __restrict__ B, int ldb,
    OT* __restrict__ C, int ldc, int K, int ntn){
  __shared__ u16 As[128 * 64];
  __shared__ u16 Bs[128 * 64];
  int xcd = g & 7, local = g >> 3;
  int mper = (ngrid >> 3) / ntn;              // m-tiles per xcd
  int bn = local % ntn;
  int bm = xcd * mper + local / ntn;
  int t = threadIdx.x, lane = t & 63, wave = t >> 6;
  int lrow = t >> 3;                          // 0..31
  int swz = (((t & 7) ^ (lrow & 7)) << 3);    // XOR-swizzled col offset (elems)
  const u16* Ag = A + (size_t)(bm * 128 + lrow) * lda + swz;
  const u16* Bg = B + (size_t)(bn * 128 + lrow) * ldb + swz;
  u16* Asd = As + t * 8;
  u16* Bsd = Bs + t * 8;
  f32x4 acc[4][4];
  #pragma unroll
  for (int mi = 0; mi < 4; ++mi)
    #pragma unroll
    for (int ni = 0; ni < 4; ++ni) acc[mi][ni] = (f32x4){0.f, 0.f, 0.f, 0.f};
  int wm = (wave & 1) << 6, wn = (wave >> 1) << 6;
  int fr = lane & 15, cbb = lane >> 4;
  for (int kt = 0; kt < K; kt += 64){
    __syncthreads();
    #pragma unroll
    for (int r = 0; r < 4; ++r){
      gload16(Ag + (size_t)(r * 32) * lda + kt, Asd + r * 2048);
      gload16(Bg + (size_t)(r * 32) * ldb + kt, Bsd + r * 2048);
    }
    __syncthreads();
    #pragma unroll
    for (int kk = 0; kk < 2; ++kk){
      bf16x8 af[4], bfr[4];
      #pragma unroll
      for (int mi = 0; mi < 4; ++mi){
        int row = wm + mi * 16 + fr;
        int pcb = ((kk << 2) + cbb) ^ (fr & 7);
        af[mi] = *(const bf16x8*)(As + row * 64 + pcb * 8);
      }
      #pragma unroll
      for (int ni = 0; ni < 4; ++ni){
        int row = wn + ni * 16 + fr;
        int pcb = ((kk << 2) + cbb) ^ (fr & 7);
        bfr[ni] = *(const bf16x8*)(Bs + row * 64 + pcb * 8);
      }
      #pragma unroll
      for (int mi = 0; mi < 4; ++mi)
        #pragma unroll
        for (int ni = 0; ni < 4; ++ni)
          acc[mi][ni] = __builtin_amdgcn_mfma_f32_16x16x32_bf16(af[mi], bfr[ni], acc[mi][ni], 0, 0, 0);
    }
  }
  int rq = lane >> 4;
  #pragma unroll
  for (int mi = 0; mi < 4; ++mi)
    #pragma unroll
    for (int ni = 0; ni < 4; ++ni){
      size_t base = (size_t)(bm * 128 + wm + mi * 16 + rq * 4) * ldc
                  + (size_t)(bn * 128 + wn + ni * 16 + fr);
      #pragma unroll
      for (int r = 0; r < 4; ++r){
        if constexpr (sizeof(OT) == 4) C[base + (size_t)r * ldc] = acc[mi][ni][r];
        else                           C[base + (size_t)r * ldc] = (OT)f2bf(acc[mi][ni][r]);
      }
    }
}

// -------------------------------------------- kA: KT + conv_w12 + rec init
__global__ __launch_bounds__(256) void kA(const float* rho_raw, const float* theta,
    const float* K12, const float* K21, const float* K22, u16* KTbf,
    const float4* k12_4, u16* W12, u64* rec){
  int blk = blockIdx.x;
  if (blk < 4096){
    int idx = blk * 256 + threadIdx.x;           // KT output idx
    int j = idx >> 10, i = idx & 1023;           // KT row j, col i
    KTbf[idx] = f2bf(kraw_at(i, j, rho_raw, theta, K12, K21, K22));
  } else if (blk < 4096 + 256){
    long g = (long)(blk - 4096) * 256 + threadIdx.x; // 65536 total
    float4 v = k12_4[g];
    u32 lo = (u32)f2bf(v.x) | ((u32)f2bf(v.y) << 16);
    u32 hi = (u32)f2bf(v.z) | ((u32)f2bf(v.w) << 16);
    ((uint2*)W12)[g] = make_uint2(lo, hi);
  } else {
    for (int i = threadIdx.x; i < 2048; i += 256) rec[i] = 0ull;
  }
}

// -------------------------------------------- kB: Ggemm || conv_u || w0
__global__ __launch_bounds__(256) void kB(const u16* KTbf, float* G,
    const float4* u4, u16* X, const float* S, const float* state, float* w0){
  int blk = blockIdx.x;
  if (blk < 64){
    gemm_body<float>(blk, 64, KTbf, 1024, KTbf, 1024, G, 1024, 1024, 8);
  } else if (blk < 64 + 32768){
    long g = (long)(blk - 64) * 256 + threadIdx.x;   // 8388608 total
    float4 v = u4[g];
    int h4 = (int)(g & 127);
    long row = g >> 7;
    u16* dst = X + row * 1024 + 512 + h4 * 4;
    u32 lo = (u32)f2bf(v.x) | ((u32)f2bf(v.y) << 16);
    u32 hi = (u32)f2bf(v.z) | ((u32)f2bf(v.w) << 16);
    *((uint2*)dst) = make_uint2(lo, hi);
  } else {
    int idx = (blk - 32832) * 256 + threadIdx.x;     // 8192 total
    int b = idx >> 9, n = idx & 511;
    const float* sr = S + n * 512;
    const float* st = state + b * 512;
    float acc = 0.f;
    for (int m2 = 0; m2 < 512; ++m2) acc += sr[m2] * st[m2];
    w0[idx] = acc;
  }
}

// ---------------------------- kC: lanczos (blocks 0..31) || GEMM1 (32..2079)
// Lanczos block b owns rows [32b,32b+32) of G in VGPRs. Per iteration:
// publish 32 y-values as self-tagged 8B records {f32,iter} (one agent leg),
// poll all 1024, then redundantly+deterministically compute alpha,w,beta in
// every block (identical FP order => identical results). Block 0 keeps
// alpha/beta^2 in LDS and runs Sturm bisection + coef at the end.
__global__ __launch_bounds__(256, 1) void kC(const float* __restrict__ G,
    u64* rec, const float* rho_raw, const float* theta, const float* log_gamma,
    float* scal, float2* coef,
    const u16* Xb, const u16* W12, u16* Bu){
  if (blockIdx.x >= LBLK){
    gemm_body<u16>(blockIdx.x - LBLK, 2048, Xb, 1024, W12, 512, Bu, 512, 512, 4);
    return;
  }
  __shared__ __align__(16) float vl[1024];  // raw v_{j-1} (full vector)
  __shared__ float red[8];
  __shared__ double sa[LM], sb2[LM + 1];
  __shared__ float sh_inv;
  int t = threadIdx.x, wave = t >> 6, lane = t & 63;
  int row0 = blockIdx.x * 32;

  // ---- my 32 G rows -> registers. wave w owns rows 8w..8w+7; lane l holds
  // floats [4l+256*i2, +4) of each row.
  f32x4 greg[8][4];
  {
    const float* gbase = G + (size_t)(row0 + wave * 8) * 1024 + lane * 4;
    #pragma unroll
    for (int rr = 0; rr < 8; ++rr)
      #pragma unroll
      for (int i2 = 0; i2 < 4; ++i2)
        greg[rr][i2] = *(const f32x4*)(gbase + (size_t)rr * 1024 + i2 * 256);
  }

  // ---- v0 raw + deterministic redundant norm (identical in every block)
  float vprevreg[4] = {0.f, 0.f, 0.f, 0.f};
  float n2tot;
  {
    float s = 0.f;
    #pragma unroll
    for (int k = 0; k < 4; ++k){
      int i = t + 256 * k;
      float v = sinf(0.613f * (float)i + 0.271f) + 0.3f * sinf(0.0247f * (float)i + 1.3f);
      vl[i] = v;
      s += v * v;
    }
    #pragma unroll
    for (int off = 32; off; off >>= 1) s += __shfl_down(s, off);
    if (lane == 0) red[wave] = s;
    __syncthreads();
    n2tot = (red[0] + red[1]) + (red[2] + red[3]);
  }
  float scl = 1.f / sqrtf(n2tot);      // 1/beta_0
  float betacoef = 0.f;                // no v_prev term at j=1
  if (t == 0) sb2[0] = 0.0;

  for (int j = 1; j <= LM; ++j){
    u64* rb = rec + ((j & 1) ? 0 : 1024);   // double buffer by parity
    // ---- y_raw(my rows) = G * v_raw; butterfly reduce so lanes 0..7 hold
    // their row's value; publish self-tagged records.
    {
      f32x4 vreg[4];
      #pragma unroll
      for (int i2 = 0; i2 < 4; ++i2)
        vreg[i2] = *((const f32x4*)vl + lane + 64 * i2);
      u64 myrec = 0ull;
      #pragma unroll
      for (int rr = 0; rr < 8; ++rr){
        float s = 0.f;
        #pragma unroll
        for (int i2 = 0; i2 < 4; ++i2){
          f32x4 g = greg[rr][i2], v = vreg[i2];
          s += g[0] * v[0] + g[1] * v[1] + g[2] * v[2] + g[3] * v[3];
        }
        #pragma unroll
        for (int off = 32; off; off >>= 1) s += __shfl_xor(s, off);
        if (lane == rr)
          myrec = ((u64)(u32)j << 32) | (u64)__float_as_uint(s);
      }
      if (lane < 8)
        __hip_atomic_store(&rb[row0 + wave * 8 + lane], myrec,
                           __ATOMIC_RELAXED, __HIP_MEMORY_SCOPE_AGENT);
    }

    // ---- poll full y: tag==j => payload valid. 4 loads kept in flight.
    float yr[4], vr[4];
    {
      u64 r0, r1, r2, r3;
      bool done = false;
      while (!done){
        r0 = __hip_atomic_load(&rb[t        ], __ATOMIC_RELAXED, __HIP_MEMORY_SCOPE_AGENT);
        r1 = __hip_atomic_load(&rb[t +  256 ], __ATOMIC_RELAXED, __HIP_MEMORY_SCOPE_AGENT);
        r2 = __hip_atomic_load(&rb[t +  512 ], __ATOMIC_RELAXED, __HIP_MEMORY_SCOPE_AGENT);
        r3 = __hip_atomic_load(&rb[t +  768 ], __ATOMIC_RELAXED, __HIP_MEMORY_SCOPE_AGENT);
        done = ((u32)(r0 >> 32) == (u32)j) && ((u32)(r1 >> 32) == (u32)j)
            && ((u32)(r2 >> 32) == (u32)j) && ((u32)(r3 >> 32) == (u32)j);
        if (!done) __builtin_amdgcn_s_sleep(1);
      }
      yr[0] = __uint_as_float((u32)r0); yr[1] = __uint_as_float((u32)r1);
      yr[2] = __uint_as_float((u32)r2); yr[3] = __uint_as_float((u32)r3);
      #pragma unroll
      for (int k = 0; k < 4; ++k) vr[k] = vl[t + 256 * k];
    }

    // ---- redundant deterministic alpha: dot = v_raw^T y_raw
    float dotp = 0.f;
    #pragma unroll
    for (int k = 0; k < 4; ++k) dotp += vr[k] * yr[k];
    #pragma unroll
    for (int off = 32; off; off >>= 1) dotp += __shfl_down(dotp, off);
    if (lane == 0) red[wave] = dotp;
    __syncthreads();
    float dot = (red[0] + red[1]) + (red[2] + red[3]);
    float alpha_f = dot * scl * scl;

    // ---- w = scl*y - alpha*vhat - beta*vprevhat (full vector, redundant)
    float n2 = 0.f;
    #pragma unroll
    for (int k = 0; k < 4; ++k){
      float vh = vr[k] * scl;
      float wv = yr[k] * scl - alpha_f * vh - betacoef * vprevreg[k];
      vprevreg[k] = vh;
      vl[t + 256 * k] = wv;            // raw next v
      n2 += wv * wv;
    }
    #pragma unroll
    for (int off = 32; off; off >>= 1) n2 += __shfl_down(n2, off);
    if (lane == 0) red[4 + wave] = n2;
    __syncthreads();                    // also orders vl[] writes vs next matvec
    n2tot = (red[4] + red[5]) + (red[6] + red[7]);
    if (n2tot < 1e-30f) n2tot = 1e-30f;

    if (t == 0){ sa[j - 1] = (double)alpha_f; sb2[j] = (double)n2tot; }
    betacoef = sqrtf(n2tot);
    scl = 1.f / betacoef;
  }

  // ---- block 0 tail: Sturm bisection for lambda_max(T), sigma, scan coef
  if (blockIdx.x != 0) return;
  __syncthreads();
  if (t < 64){
    int lane2 = t;
    double lo = sa[0], hi = sa[0], bmax = 0.0;
    for (int i = 0; i < LM; ++i){
      if (sa[i] > lo) lo = sa[i];
      double bl = (i > 0) ? sqrt(fmax(sb2[i], 0.0)) : 0.0;
      double br = (i < LM - 1) ? sqrt(fmax(sb2[i + 1], 0.0)) : 0.0;
      double g = sa[i] + bl + br;
      if (g > hi) hi = g;
      if (i < LM - 1 && sb2[i + 1] > bmax) bmax = sb2[i + 1];
    }
    hi = hi + 1e-6 * fabs(hi) + 1e-20;
    lo = lo - 1e-6 * fabs(lo) - 1e-20;
    double pivmin = 1e-30 * bmax + 1e-300;
    for (int round = 0; round < 6; ++round){
      double x = lo + (hi - lo) * ((double)(lane2 + 1) / 65.0);
      double d = sa[0] - x; int cnt = (d < 0.0);
      for (int i = 1; i < LM; ++i){
        if (fabs(d) < pivmin) d = -pivmin;
        d = (sa[i] - x) - sb2[i] / d;
        cnt += (d < 0.0);
      }
      unsigned long long mk = __ballot(cnt >= LM);
      int bpos = (mk == 0ULL) ? 64 : (__ffsll((unsigned long long)mk) - 1);
      double xlo = __shfl(x, (bpos == 0) ? 0 : bpos - 1);
      double xhi = __shfl(x, (bpos == 64) ? 63 : bpos);
      double nlo = (bpos == 0) ? lo : xlo;
      double nhi = (bpos == 64) ? hi : xhi;
      lo = nlo; hi = nhi;
    }
    if (lane2 == 0){
      double lam = 0.5 * (lo + hi);
      double sig = (lam > 0.0) ? sqrt(lam) : 0.0;
      if (sig < 1e-5) sig = 1e-5;
      double spp = sig + 0.002;
      float inv = (float)(1.0 / spp);
      float g = expf(log_gamma[0]);
      scal[0] = inv; scal[1] = g; scal[2] = g * inv;
      sh_inv = inv;
    }
  }
  __syncthreads();
  float inv = sh_inv;
  float rho = (1.f / (1.f + expf(-rho_raw[t]))) * 0.999f;
  float c = cosf(theta[t]), s = sinf(theta[t]);
  coef[t] = make_float2(rho * c * inv, rho * s * inv);
}

// ------------------------------ kD: scan (blocks 0..511) || wcat (512..2559)
__global__ __launch_bounds__(256) void kD(const u32* Bu, const float2* coef,
    const float* w0, const float* scal, u16* X,
    const float* K21, const float* K22, u16* W){
  int blk = blockIdx.x;
  if (blk >= 512){
    int idx = (blk - 512) * 256 + threadIdx.x;       // 524288 total
    int o = idx >> 10, c = idx & 1023;
    float inv = scal[0], gi = scal[2];
    float v = (c < 512) ? K21[o * 512 + c] * inv : K22[o * 512 + (c - 512)] * gi;
    W[idx] = f2bf(v);
    return;
  }
  int b = blk >> 5;                  // 16 batches
  int c = blk & 31;                  // 32 chunks of 128
  int p = threadIdx.x;               // 256 pairs
  float2 ab = coef[p];
  float gi = scal[2];
  int t0 = c * CHUNK;
  float wx, wy; int t;
  if (c == 0){ wx = w0[b * 512 + 2 * p]; wy = w0[b * 512 + 2 * p + 1]; t = 0; }
  else { wx = 0.f; wy = 0.f; t = t0 - WARM; }
  const u32* bub = Bu + (size_t)b * 4096 * 256;
  u16* xb = X + (size_t)b * 4096 * 1024;
  for (; t < t0; ++t){
    u32 v = bub[(size_t)t * 256 + p];
    float bx = __uint_as_float(v << 16);
    float by = __uint_as_float(v & 0xffff0000u);
    float nx = ab.x * wx - ab.y * wy + gi * bx;
    float ny = ab.y * wx + ab.x * wy + gi * by;
    wx = nx; wy = ny;
  }
  for (; t < t0 + CHUNK; ++t){
    u32 pk = (u32)f2bf(wx) | ((u32)f2bf(wy) << 16);
    *(u32*)(xb + (size_t)t * 1024 + 2 * p) = pk;
    u32 v = bub[(size_t)t * 256 + p];
    float bx = __uint_as_float(v << 16);
    float by = __uint_as_float(v & 0xffff0000u);
    float nx = ab.x * wx - ab.y * wy + gi * bx;
    float ny = ab.y * wx + ab.x * wy + gi * by;
    wx = nx; wy = ny;
  }
}

// standalone GEMM wrapper (GEMM2)
template <typename OT>
__global__ __launch_bounds__(256) void gemm_nt(const u16* __restrict__ A, int lda,
    const u16* __restrict__ B, int ldb, OT* __restrict__ C, int ldc, int K, int ntn){
  gemm_body<OT>(blockIdx.x, gridDim.x, A, lda, B, ldb, C, ldc, K, ntn);
}

// ------------------------------------------------------------------- launcher
extern "C" void kernel_launch(void* const* d_in, const int* in_sizes, int n_in,
                              void* d_out, int out_size, void* d_ws, size_t ws_size,
                              hipStream_t stream){
  const float* u        = (const float*)d_in[0];
  const float* state    = (const float*)d_in[1];
  const float* S        = (const float*)d_in[2];
  const float* rho_raw  = (const float*)d_in[3];
  const float* theta    = (const float*)d_in[4];
  const float* K12      = (const float*)d_in[5];
  const float* K21      = (const float*)d_in[6];
  const float* K22      = (const float*)d_in[7];
  const float* log_gamma= (const float*)d_in[8];

  char* w = (char*)d_ws;
  size_t off = 0;
  auto alloc = [&](size_t bytes)->void*{
    void* p = w + off;
    off = (off + bytes + 255) & ~(size_t)255;
    return p;
  };
  u64*    rec   = (u64*)alloc(2048 * 8);       // 2 x 1024 self-tagged records
  float*  scal  = (float*)alloc(64);
  float2* coef  = (float2*)alloc(256 * 8);
  float*  w0    = (float*)alloc(16 * 512 * 4);
  u16*    KTbf  = (u16*)alloc((size_t)1024 * 1024 * 2);
  float*  G     = (float*)alloc((size_t)1024 * 1024 * 4);
  u16*    W12   = (u16*)alloc((size_t)512 * 512 * 2);
  u16*    Wcat  = (u16*)alloc((size_t)512 * 1024 * 2);
  u16*    Xb    = (u16*)alloc((size_t)65536 * 1024 * 2);
  // Bu (bf16, 67 MB) aliases d_out; consumed by scan before GEMM2 overwrites.
  u16*    Bu    = (u16*)d_out;

  // kA: KT (4096) + conv_w12 (256) + rec init (1)
  kA<<<4353, 256, 0, stream>>>(rho_raw, theta, K12, K21, K22, KTbf,
                               (const float4*)K12, W12, rec);
  // kB: G = KT @ KT^T (64, first) || conv_u (32768) || w0 (32)
  kB<<<32864, 256, 0, stream>>>(KTbf, G, (const float4*)u, Xb, S, state, w0);
  // kC: lanczos+finalize (32, first) || GEMM1 Bu = u_bf16 @ K12^T (2048)
  kC<<<LBLK + 2048, 256, 0, stream>>>(G, rec, rho_raw, theta, log_gamma,
                                      scal, coef, Xb + 512, W12, Bu);
  // kD: scan (512, first) || build_wcat (2048)
  kD<<<2560, 256, 0, stream>>>((const u32*)Bu, coef, w0, scal, Xb, K21, K22, Wcat);
  // GEMM2: y = [pre|u] @ [K21n | gamma*K22n]^T  (M=65536, N=512, K=1024)
  gemm_nt<float><<<2048, 256, 0, stream>>>(Xb, 1024, Wcat, 1024, (float*)d_out, 512, 1024, 4);
}